// Round 6
// baseline (1617.136 us; speedup 1.0000x reference)
//
#include <hip/hip_runtime.h>
#include <math.h>

#define BDIM 256

// ---------------------------------------------------------------------------
// jax.image.resize (bilinear/triangle, antialias=True) tap weights.
// ---------------------------------------------------------------------------
__device__ __forceinline__ int resize_taps(int out_n, int o, int in_n,
                                           float* w, int* i0) {
  float inv_scale = (float)in_n / (float)out_n;
  float ks = inv_scale > 1.f ? inv_scale : 1.f;
  float sf = ((float)o + 0.5f) * inv_scale - 0.5f;
  int lo = (int)ceilf(sf - ks);
  int hi = (int)floorf(sf + ks);
  if (lo < 0) lo = 0;
  if (hi > in_n - 1) hi = in_n - 1;
  int n = hi - lo + 1;
  float sum = 0.f;
  for (int k = 0; k < n; ++k) {
    float t = 1.f - fabsf((float)(lo + k) - sf) / ks;
    t = t > 0.f ? t : 0.f;
    w[k] = t;
    sum += t;
  }
  float inv = 1.f / sum;
  for (int k = 0; k < n; ++k) w[k] *= inv;
  *i0 = lo;
  return n;
}

__device__ __forceinline__ float resize_one(const float* __restrict__ plane,
                                            int Hi, int Wi, int oy, int ox,
                                            int Ho, int Wo) {
  float wy[8], wx[8];
  int y0, x0;
  int ny = resize_taps(Ho, oy, Hi, wy, &y0);
  int nx = resize_taps(Wo, ox, Wi, wx, &x0);
  float acc = 0.f;
  for (int a = 0; a < ny; ++a) {
    const float* row = plane + (y0 + a) * Wi + x0;
    float r = 0.f;
    for (int b = 0; b < nx; ++b) r += wx[b] * row[b];
    acc += wy[a] * r;
  }
  return acc;
}

// x1s (64ch 64->32) and x2s (64ch 64->128) in one launch.
__global__ void k_resize12(const float* __restrict__ x, float* __restrict__ x1s,
                           float* __restrict__ x2s) {
  int idx = blockIdx.x * BDIM + threadIdx.x;
  if (idx < 64 * 32 * 32) {
    int ox = idx & 31, oy = (idx >> 5) & 31, c = idx >> 10;
    x1s[idx] = resize_one(x + c * 4096, 64, 64, oy, ox, 32, 32);
  } else {
    int j = idx - 65536;
    if (j < 64 * 128 * 128) {
      int ox = j & 127, oy = (j >> 7) & 127, c = j >> 14;
      x2s[j] = resize_one(x + c * 4096, 64, 64, oy, ox, 128, 128);
    }
  }
}

// generic (used for x3s: 64ch 128->256)
__global__ void k_resize(const float* __restrict__ in, float* __restrict__ out,
                         int C, int Hi, int Wi, int Ho, int Wo) {
  int idx = blockIdx.x * BDIM + threadIdx.x;
  if (idx >= C * Ho * Wo) return;
  int ox = idx % Wo;
  int t = idx / Wo;
  int oy = t % Ho;
  int c = t / Ho;
  out[idx] = resize_one(in + (size_t)c * Hi * Wi, Hi, Wi, oy, ox, Ho, Wo);
}

// ---------------------------------------------------------------------------
// Weight transpose: deform w_c[i] (16,64,3,3) -> [k][c][o] (9216 each);
// conv w_off[i] (18,64,3,3) -> [k][c][o] (10368 each) at base 36864.
// ---------------------------------------------------------------------------
__global__ void k_wtrans(const float* __restrict__ d0, const float* __restrict__ d1,
                         const float* __restrict__ d2, const float* __restrict__ d3,
                         const float* __restrict__ c0, const float* __restrict__ c1,
                         const float* __restrict__ c2, const float* __restrict__ c3,
                         float* __restrict__ dst) {
  int idx = blockIdx.x * BDIM + threadIdx.x;
  if (idx < 36864) {
    int i = idx / 9216, r = idx % 9216;
    int o = r % 16, t = r / 16, c = t % 64, k = t / 64;
    const float* s = i == 0 ? d0 : i == 1 ? d1 : i == 2 ? d2 : d3;
    dst[idx] = s[(o * 64 + c) * 9 + k];
  } else if (idx < 36864 + 41472) {
    int j = idx - 36864;
    int i = j / 10368, r = j % 10368;
    int o = r % 18, t = r / 18, c = t % 64, k = t / 64;
    const float* s = i == 0 ? c0 : i == 1 ? c1 : i == 2 ? c2 : c3;
    dst[idx] = s[(o * 64 + c) * 9 + k];
  }
}

// ---------------------------------------------------------------------------
// Merged 3x3 conv (Cin=64 -> 18). Block = 512 thr = 8 waves; wave g owns
// channels [8g,8g+8) for 64 px (lane). Weights [k][c][o] via uniform s_loads.
// ---------------------------------------------------------------------------
struct CArgs {
  const float* in[4];
  const float* wT[4];
  const float* bias[4];
  float* out[4];
  int cut0, cut1, cut2;
};

__global__ __launch_bounds__(512, 8) void k_conv_all(CArgs A) {
  int b = blockIdx.x;
  int s = (b >= A.cut0) + (b >= A.cut1) + (b >= A.cut2);
  int b0 = (s == 0) ? 0 : (s == 1 ? A.cut0 : (s == 2 ? A.cut1 : A.cut2));
  int H = 32 << s, W = H, lw = 5 + s, HW = H * W;
  const float* in = A.in[s];
  const float* wT = A.wT[s];
  const float* bias = A.bias[s];
  float* out = A.out[s];
  int tid = threadIdx.x, lane = tid & 63, g = tid >> 6;
  int p = (b - b0) * 64 + lane;
  int py = p >> lw, px = p & (W - 1);
  float acc[18];
#pragma unroll
  for (int o = 0; o < 18; ++o) acc[o] = 0.f;
  const float* ipg = in + (size_t)(g * 8) * HW;
#pragma unroll
  for (int ky = 0; ky < 3; ++ky) {
#pragma unroll
    for (int kx = 0; kx < 3; ++kx) {
      int k = ky * 3 + kx;
      int yy = py + ky - 1, xx = px + kx - 1;
      float msk = (yy >= 0 && yy < H && xx >= 0 && xx < W) ? 1.f : 0.f;
      int ai = min(max(yy, 0), H - 1) * W + min(max(xx, 0), W - 1);
      const float* ip = ipg + ai;
      const float* wk = wT + (size_t)(k * 64 + g * 8) * 18;
#pragma unroll
      for (int c = 0; c < 8; ++c, ip += HW, wk += 18) {
        float v = *ip * msk;
#pragma unroll
        for (int o = 0; o < 18; ++o) acc[o] += wk[o] * v;
      }
    }
  }
  __shared__ float red[7][64][19];
  if (g) {
#pragma unroll
    for (int o = 0; o < 18; ++o) red[g - 1][lane][o] = acc[o];
  }
  __syncthreads();
  if (!g) {
#pragma unroll
    for (int o = 0; o < 18; ++o) {
      float v = acc[o] + bias[o];
#pragma unroll
      for (int r = 0; r < 7; ++r) v += red[r][lane][o];
      out[(size_t)o * HW + p] = v;
    }
  }
}

// ---------------------------------------------------------------------------
// Merged deformable 3x3 conv (Cin=64 -> 16) + leaky. Block = 512 thr = 8
// waves; wave g owns channels [8g,8g+8) for 64 px. k-outer, taps on the fly
// (low VGPR); x-clamp folded into weight permutation. Weights [k][c][o].
// ---------------------------------------------------------------------------
struct DArgs {
  const float* in[4];
  const float* off[4];
  const float* wT[4];
  const float* bias[4];
  float* out[4];
  int cut0, cut1, cut2;
};

__global__ __launch_bounds__(512, 8) void k_deform_all(DArgs A) {
  int b = blockIdx.x;
  int s = (b >= A.cut0) + (b >= A.cut1) + (b >= A.cut2);
  int b0 = (s == 0) ? 0 : (s == 1 ? A.cut0 : (s == 2 ? A.cut1 : A.cut2));
  int H = 32 << s, W = H, lw = 5 + s, HW = H * W;
  int pad = 4 - s, dil = 4 - s;
  const float* in = A.in[s];
  const float* off = A.off[s];
  const float* wT = A.wT[s];
  const float* bias = A.bias[s];
  float* out = A.out[s];
  int tid = threadIdx.x, lane = tid & 63, g = tid >> 6;
  int p = (b - b0) * 64 + lane;
  int py_ = p >> lw, px_ = p & (W - 1);

  float acc[16];
#pragma unroll
  for (int o = 0; o < 16; ++o) acc[o] = 0.f;
  const float* ipg = in + (size_t)(g * 8) * HW;
#pragma unroll
  for (int ky = 0; ky < 3; ++ky) {
#pragma unroll
    for (int kx = 0; kx < 3; ++kx) {
      int k = ky * 3 + kx;
      float dy = off[(size_t)(2 * k) * HW + p];
      float dx = off[(size_t)(2 * k + 1) * HW + p];
      float pyf = (float)(py_ - pad + ky * dil) + dy;
      float pxf = (float)(px_ - pad + kx * dil) + dx;
      float fy0 = floorf(pyf), fx0 = floorf(pxf);
      float wy = pyf - fy0, wxv = pxf - fx0;
      int y0 = (int)fy0, x0 = (int)fx0;
      float xg = (x0 >= -1 && x0 <= W - 1) ? 1.f : 0.f;
      float r0 = (1.f - wy) * ((y0 >= 0 && y0 < H) ? xg : 0.f);
      float r1 = wy * ((y0 + 1 >= 0 && y0 + 1 < H) ? xg : 0.f);
      float cl = 1.f - wxv, cr = wxv;
      bool xlo = x0 < 0, xhi = x0 > W - 2;
      float W00 = xlo ? r0 * cr : (xhi ? 0.f : r0 * cl);
      float W01 = xlo ? 0.f : (xhi ? r0 * cl : r0 * cr);
      float W10 = xlo ? r1 * cr : (xhi ? 0.f : r1 * cl);
      float W11 = xlo ? 0.f : (xhi ? r1 * cl : r1 * cr);
      int ax = min(max(x0, 0), W - 2);
      int cy0 = min(max(y0, 0), H - 1);
      int cy1 = min(max(y0 + 1, 0), H - 1);
      int A0 = cy0 * W + ax, A1 = cy1 * W + ax;
      const float* ip = ipg;
      const float* wk = wT + (size_t)(k * 64 + g * 8) * 16;
#pragma unroll
      for (int c = 0; c < 8; ++c, ip += HW, wk += 16) {
        const float* r0p = ip + A0;
        const float* r1p = ip + A1;
        float sv = W00 * r0p[0] + W01 * r0p[1] + W10 * r1p[0] + W11 * r1p[1];
#pragma unroll
        for (int o = 0; o < 16; ++o) acc[o] += wk[o] * sv;
      }
    }
  }
  __shared__ float red[7][64][17];
  if (g) {
#pragma unroll
    for (int o = 0; o < 16; ++o) red[g - 1][lane][o] = acc[o];
  }
  __syncthreads();
  if (!g) {
#pragma unroll
    for (int o = 0; o < 16; ++o) {
      float v = acc[o] + bias[o];
#pragma unroll
      for (int r = 0; r < 7; ++r) v += red[r][lane][o];
      v = v >= 0.f ? v : 0.01f * v;
      out[(size_t)o * HW + p] = v;
    }
  }
}

__device__ __forceinline__ float gelu_f(float x) {
  return 0.5f * x * (1.f + erff(x * 0.70710678118654752f));
}

// Fused: x1r/x2r/x3r gathered on the fly from a1/a2/a3, + gelu combine.
__global__ void k_final(const float* __restrict__ a0, const float* __restrict__ a1,
                        const float* __restrict__ a2, const float* __restrict__ a3,
                        float* __restrict__ out) {
  int i = blockIdx.x * BDIM + threadIdx.x;  // [0, 65536)
  int x = i & 63, y = (i >> 6) & 63, c = i >> 12;
  float x1r = resize_one(a1 + c * 1024, 32, 32, y, x, 64, 64);
  float x2r = resize_one(a2 + c * 16384, 128, 128, y, x, 64, 64);
  float x3r = resize_one(a3 + c * 65536, 256, 256, y, x, 64, 64);
  float av = a0[i];
  float l = gelu_f(x1r);
  float m = gelu_f(av - l);
  float h = gelu_f(x2r - av);
  float sv = gelu_f(x3r - x2r);
  out[i] = l;
  out[65536 + i] = m;
  out[131072 + i] = h;
  out[196608 + i] = sv;
}

static inline int cdiv(int a, int b) { return (a + b - 1) / b; }

extern "C" void kernel_launch(void* const* d_in, const int* in_sizes, int n_in,
                              void* d_out, int out_size, void* d_ws, size_t ws_size,
                              hipStream_t stream) {
  (void)in_sizes; (void)n_in; (void)out_size; (void)ws_size;
  const float* x = (const float*)d_in[0];
  const float* w_off[4] = {(const float*)d_in[1], (const float*)d_in[5],
                           (const float*)d_in[9], (const float*)d_in[13]};
  const float* b_off[4] = {(const float*)d_in[2], (const float*)d_in[6],
                           (const float*)d_in[10], (const float*)d_in[14]};
  const float* w_c[4] = {(const float*)d_in[3], (const float*)d_in[7],
                         (const float*)d_in[11], (const float*)d_in[15]};
  const float* b_c[4] = {(const float*)d_in[4], (const float*)d_in[8],
                         (const float*)d_in[12], (const float*)d_in[16]};
  float* out = (float*)d_out;

  // Workspace (floats), lifetime-aliased; peak 7,166,464 f = 28.7 MB.
  float* ws = (float*)d_ws;
  float* a0 = ws;                  // [0, 65536)
  float* a1 = ws + 65536;          // [65536, 81920)
  float* a2 = ws + 81920;          // [81920, 344064)
  float* wT = ws + 344064;         // [344064, 422400)
  float* x1s = ws + 422400;        // [422400, 487936)
  float* off1 = ws + 487936;       // [487936, 506368)
  float* off0 = ws + 506368;       // [506368, 580096)
  float* off2 = ws + 580096;       // [580096, 875008)
  float* x2s = ws + 875008;        // [875008, 1923584)
  float* off3 = ws + 422400;       // ALIAS x1s..x2s-part; written after both dead
  float* x3s = ws + 1923584;       // [1923584, 6117888)
  float* a3 = ws + 6117888;        // [6117888, 7166464)
  float* wTd = wT;                 // 4 x 9216
  float* wTc = wT + 36864;         // 4 x 10368

  // 1. weight transpose + pyramid level 1/2 and 2x
  k_wtrans<<<cdiv(78336, BDIM), BDIM, 0, stream>>>(
      w_c[0], w_c[1], w_c[2], w_c[3], w_off[0], w_off[1], w_off[2], w_off[3], wT);
  k_resize12<<<cdiv(65536 + 1048576, BDIM), BDIM, 0, stream>>>(x, x1s, x2s);

  // 2. conv + deform for scales 0..2 (merged; cuts 16/80/336)
  CArgs ca;
  DArgs da;
  const float* ins[4] = {x1s, x, x2s, x3s};
  float* offs[4] = {off1, off0, off2, off3};
  float* as[4] = {a1, a0, a2, a3};
  for (int s = 0; s < 4; ++s) {
    ca.in[s] = ins[s];
    ca.wT[s] = wTc + s * 10368;
    ca.bias[s] = b_off[s];
    ca.out[s] = offs[s];
    da.in[s] = ins[s];
    da.off[s] = offs[s];
    da.wT[s] = wTd + (3 - s) * 9216;
    da.bias[s] = b_c[3 - s];
    da.out[s] = as[s];
  }
  ca.cut0 = 16; ca.cut1 = 80; ca.cut2 = 336;
  da.cut0 = 16; da.cut1 = 80; da.cut2 = 336;
  k_conv_all<<<336, 512, 0, stream>>>(ca);
  k_deform_all<<<336, 512, 0, stream>>>(da);

  // 3. x3s (needs x2s; x1s/off0-2 now dead)
  k_resize<<<cdiv(64 * 256 * 256, BDIM), BDIM, 0, stream>>>(x2s, x3s, 64, 128, 128, 256, 256);

  // 4. conv + deform for scale 3 (cuts 0/0/0 -> all blocks s=3)
  CArgs ca3 = ca;
  DArgs da3 = da;
  ca3.cut0 = 0; ca3.cut1 = 0; ca3.cut2 = 0;
  da3.cut0 = 0; da3.cut1 = 0; da3.cut2 = 0;
  k_conv_all<<<1024, 512, 0, stream>>>(ca3);
  k_deform_all<<<1024, 512, 0, stream>>>(da3);

  // 5. fused resize + gelu combine
  k_final<<<cdiv(65536, BDIM), BDIM, 0, stream>>>(a0, a1, a2, a3, out);
}

// Round 7
// 276.514 us; speedup vs baseline: 5.8483x; 5.8483x over previous
//
#include <hip/hip_runtime.h>
#include <math.h>

#define BDIM 256

// ---------------------------------------------------------------------------
// jax.image.resize (bilinear/triangle, antialias=True) tap weights.
// ---------------------------------------------------------------------------
__device__ __forceinline__ int resize_taps(int out_n, int o, int in_n,
                                           float* w, int* i0) {
  float inv_scale = (float)in_n / (float)out_n;
  float ks = inv_scale > 1.f ? inv_scale : 1.f;
  float sf = ((float)o + 0.5f) * inv_scale - 0.5f;
  int lo = (int)ceilf(sf - ks);
  int hi = (int)floorf(sf + ks);
  if (lo < 0) lo = 0;
  if (hi > in_n - 1) hi = in_n - 1;
  int n = hi - lo + 1;
  float sum = 0.f;
  for (int k = 0; k < n; ++k) {
    float t = 1.f - fabsf((float)(lo + k) - sf) / ks;
    t = t > 0.f ? t : 0.f;
    w[k] = t;
    sum += t;
  }
  float inv = 1.f / sum;
  for (int k = 0; k < n; ++k) w[k] *= inv;
  *i0 = lo;
  return n;
}

__device__ __forceinline__ float resize_one(const float* __restrict__ plane,
                                            int Hi, int Wi, int oy, int ox,
                                            int Ho, int Wo) {
  float wy[8], wx[8];
  int y0, x0;
  int ny = resize_taps(Ho, oy, Hi, wy, &y0);
  int nx = resize_taps(Wo, ox, Wi, wx, &x0);
  float acc = 0.f;
  for (int a = 0; a < ny; ++a) {
    const float* row = plane + (y0 + a) * Wi + x0;
    float r = 0.f;
    for (int b = 0; b < nx; ++b) r += wx[b] * row[b];
    acc += wy[a] * r;
  }
  return acc;
}

// x1s (64ch 64->32) and x2s (64ch 64->128) in one launch.
__global__ void k_resize12(const float* __restrict__ x, float* __restrict__ x1s,
                           float* __restrict__ x2s) {
  int idx = blockIdx.x * BDIM + threadIdx.x;
  if (idx < 64 * 32 * 32) {
    int ox = idx & 31, oy = (idx >> 5) & 31, c = idx >> 10;
    x1s[idx] = resize_one(x + c * 4096, 64, 64, oy, ox, 32, 32);
  } else {
    int j = idx - 65536;
    if (j < 64 * 128 * 128) {
      int ox = j & 127, oy = (j >> 7) & 127, c = j >> 14;
      x2s[j] = resize_one(x + c * 4096, 64, 64, oy, ox, 128, 128);
    }
  }
}

// generic (used for x3s: 64ch 128->256)
__global__ void k_resize(const float* __restrict__ in, float* __restrict__ out,
                         int C, int Hi, int Wi, int Ho, int Wo) {
  int idx = blockIdx.x * BDIM + threadIdx.x;
  if (idx >= C * Ho * Wo) return;
  int ox = idx % Wo;
  int t = idx / Wo;
  int oy = t % Ho;
  int c = t / Ho;
  out[idx] = resize_one(in + (size_t)c * Hi * Wi, Hi, Wi, oy, ox, Ho, Wo);
}

// ---------------------------------------------------------------------------
// Weight transpose: deform w_c[i] (16,64,3,3) -> [k][c][o] (9216 each);
// conv w_off[i] (18,64,3,3) -> [k][c][o] (10368 each) at base 36864.
// ---------------------------------------------------------------------------
__global__ void k_wtrans(const float* __restrict__ d0, const float* __restrict__ d1,
                         const float* __restrict__ d2, const float* __restrict__ d3,
                         const float* __restrict__ c0, const float* __restrict__ c1,
                         const float* __restrict__ c2, const float* __restrict__ c3,
                         float* __restrict__ dst) {
  int idx = blockIdx.x * BDIM + threadIdx.x;
  if (idx < 36864) {
    int i = idx / 9216, r = idx % 9216;
    int o = r % 16, t = r / 16, c = t % 64, k = t / 64;
    const float* s = i == 0 ? d0 : i == 1 ? d1 : i == 2 ? d2 : d3;
    dst[idx] = s[(o * 64 + c) * 9 + k];
  } else if (idx < 36864 + 41472) {
    int j = idx - 36864;
    int i = j / 10368, r = j % 10368;
    int o = r % 18, t = r / 18, c = t % 64, k = t / 64;
    const float* s = i == 0 ? c0 : i == 1 ? c1 : i == 2 ? c2 : c3;
    dst[idx] = s[(o * 64 + c) * 9 + k];
  }
}

// ---------------------------------------------------------------------------
// Merged 3x3 conv (Cin=64 -> 18). Block = 512 thr = 8 waves; wave g owns
// channels [8g,8g+8) for 64 px (lane). Weights [k][c][o] via uniform s_loads.
// launch_bounds(512,4): 128-VGPR budget -- do NOT force 8 waves/EU (R6 spill).
// ---------------------------------------------------------------------------
struct CArgs {
  const float* in[4];
  const float* wT[4];
  const float* bias[4];
  float* out[4];
  int cut0, cut1, cut2;
};

__global__ __launch_bounds__(512, 4) void k_conv_all(CArgs A) {
  int b = blockIdx.x;
  int s = (b >= A.cut0) + (b >= A.cut1) + (b >= A.cut2);
  int b0 = (s == 0) ? 0 : (s == 1 ? A.cut0 : (s == 2 ? A.cut1 : A.cut2));
  int H = 32 << s, W = H, lw = 5 + s, HW = H * W;
  const float* in = A.in[s];
  const float* wT = A.wT[s];
  const float* bias = A.bias[s];
  float* out = A.out[s];
  int tid = threadIdx.x, lane = tid & 63;
  int g = __builtin_amdgcn_readfirstlane(tid >> 6);
  int p = (b - b0) * 64 + lane;
  int py = p >> lw, px = p & (W - 1);
  float acc[18];
#pragma unroll
  for (int o = 0; o < 18; ++o) acc[o] = 0.f;
  const float* ipg = in + (size_t)(g * 8) * HW;
#pragma unroll
  for (int ky = 0; ky < 3; ++ky) {
#pragma unroll
    for (int kx = 0; kx < 3; ++kx) {
      int k = ky * 3 + kx;
      int yy = py + ky - 1, xx = px + kx - 1;
      float msk = (yy >= 0 && yy < H && xx >= 0 && xx < W) ? 1.f : 0.f;
      int ai = min(max(yy, 0), H - 1) * W + min(max(xx, 0), W - 1);
      const float* ip = ipg + ai;
      const float* wk = wT + (size_t)(k * 64 + g * 8) * 18;
#pragma unroll
      for (int c = 0; c < 8; ++c, ip += HW, wk += 18) {
        float v = *ip * msk;
#pragma unroll
        for (int o = 0; o < 18; ++o) acc[o] += wk[o] * v;
      }
    }
  }
  __shared__ float red[7][64][19];
  int gv = tid >> 6;
  if (gv) {
#pragma unroll
    for (int o = 0; o < 18; ++o) red[gv - 1][lane][o] = acc[o];
  }
  __syncthreads();
  if (!gv) {
#pragma unroll
    for (int o = 0; o < 18; ++o) {
      float v = acc[o] + bias[o];
#pragma unroll
      for (int r = 0; r < 7; ++r) v += red[r][lane][o];
      out[(size_t)o * HW + p] = v;
    }
  }
}

// ---------------------------------------------------------------------------
// Merged deformable 3x3 conv (Cin=64 -> 16) + leaky. Block = 512 thr = 8
// waves; wave g owns channels [8g,8g+8) for 64 px. k-outer, taps on the fly;
// x-clamp folded into weight permutation. Weights [k][c][o].
// ---------------------------------------------------------------------------
struct DArgs {
  const float* in[4];
  const float* off[4];
  const float* wT[4];
  const float* bias[4];
  float* out[4];
  int cut0, cut1, cut2;
};

__global__ __launch_bounds__(512, 4) void k_deform_all(DArgs A) {
  int b = blockIdx.x;
  int s = (b >= A.cut0) + (b >= A.cut1) + (b >= A.cut2);
  int b0 = (s == 0) ? 0 : (s == 1 ? A.cut0 : (s == 2 ? A.cut1 : A.cut2));
  int H = 32 << s, W = H, lw = 5 + s, HW = H * W;
  int pad = 4 - s, dil = 4 - s;
  const float* in = A.in[s];
  const float* off = A.off[s];
  const float* wT = A.wT[s];
  const float* bias = A.bias[s];
  float* out = A.out[s];
  int tid = threadIdx.x, lane = tid & 63;
  int g = __builtin_amdgcn_readfirstlane(tid >> 6);
  int p = (b - b0) * 64 + lane;
  int py_ = p >> lw, px_ = p & (W - 1);

  float acc[16];
#pragma unroll
  for (int o = 0; o < 16; ++o) acc[o] = 0.f;
  const float* ipg = in + (size_t)(g * 8) * HW;
#pragma unroll
  for (int ky = 0; ky < 3; ++ky) {
#pragma unroll
    for (int kx = 0; kx < 3; ++kx) {
      int k = ky * 3 + kx;
      float dy = off[(size_t)(2 * k) * HW + p];
      float dx = off[(size_t)(2 * k + 1) * HW + p];
      float pyf = (float)(py_ - pad + ky * dil) + dy;
      float pxf = (float)(px_ - pad + kx * dil) + dx;
      float fy0 = floorf(pyf), fx0 = floorf(pxf);
      float wy = pyf - fy0, wxv = pxf - fx0;
      int y0 = (int)fy0, x0 = (int)fx0;
      float xg = (x0 >= -1 && x0 <= W - 1) ? 1.f : 0.f;
      float r0 = (1.f - wy) * ((y0 >= 0 && y0 < H) ? xg : 0.f);
      float r1 = wy * ((y0 + 1 >= 0 && y0 + 1 < H) ? xg : 0.f);
      float cl = 1.f - wxv, cr = wxv;
      bool xlo = x0 < 0, xhi = x0 > W - 2;
      float W00 = xlo ? r0 * cr : (xhi ? 0.f : r0 * cl);
      float W01 = xlo ? 0.f : (xhi ? r0 * cl : r0 * cr);
      float W10 = xlo ? r1 * cr : (xhi ? 0.f : r1 * cl);
      float W11 = xlo ? 0.f : (xhi ? r1 * cl : r1 * cr);
      int ax = min(max(x0, 0), W - 2);
      int cy0 = min(max(y0, 0), H - 1);
      int cy1 = min(max(y0 + 1, 0), H - 1);
      int A0 = cy0 * W + ax, A1 = cy1 * W + ax;
      const float* ip = ipg;
      const float* wk = wT + (size_t)(k * 64 + g * 8) * 16;
#pragma unroll
      for (int c = 0; c < 8; ++c, ip += HW, wk += 16) {
        const float* r0p = ip + A0;
        const float* r1p = ip + A1;
        float sv = W00 * r0p[0] + W01 * r0p[1] + W10 * r1p[0] + W11 * r1p[1];
#pragma unroll
        for (int o = 0; o < 16; ++o) acc[o] += wk[o] * sv;
      }
    }
  }
  __shared__ float red[7][64][17];
  int gv = tid >> 6;
  if (gv) {
#pragma unroll
    for (int o = 0; o < 16; ++o) red[gv - 1][lane][o] = acc[o];
  }
  __syncthreads();
  if (!gv) {
#pragma unroll
    for (int o = 0; o < 16; ++o) {
      float v = acc[o] + bias[o];
#pragma unroll
      for (int r = 0; r < 7; ++r) v += red[r][lane][o];
      v = v >= 0.f ? v : 0.01f * v;
      out[(size_t)o * HW + p] = v;
    }
  }
}

__device__ __forceinline__ float gelu_f(float x) {
  return 0.5f * x * (1.f + erff(x * 0.70710678118654752f));
}

// Fused: x1r/x2r/x3r gathered on the fly from a1/a2/a3, + gelu combine.
__global__ void k_final(const float* __restrict__ a0, const float* __restrict__ a1,
                        const float* __restrict__ a2, const float* __restrict__ a3,
                        float* __restrict__ out) {
  int i = blockIdx.x * BDIM + threadIdx.x;  // [0, 65536)
  int x = i & 63, y = (i >> 6) & 63, c = i >> 12;
  float x1r = resize_one(a1 + c * 1024, 32, 32, y, x, 64, 64);
  float x2r = resize_one(a2 + c * 16384, 128, 128, y, x, 64, 64);
  float x3r = resize_one(a3 + c * 65536, 256, 256, y, x, 64, 64);
  float av = a0[i];
  float l = gelu_f(x1r);
  float m = gelu_f(av - l);
  float h = gelu_f(x2r - av);
  float sv = gelu_f(x3r - x2r);
  out[i] = l;
  out[65536 + i] = m;
  out[131072 + i] = h;
  out[196608 + i] = sv;
}

static inline int cdiv(int a, int b) { return (a + b - 1) / b; }

extern "C" void kernel_launch(void* const* d_in, const int* in_sizes, int n_in,
                              void* d_out, int out_size, void* d_ws, size_t ws_size,
                              hipStream_t stream) {
  (void)in_sizes; (void)n_in; (void)out_size; (void)ws_size;
  const float* x = (const float*)d_in[0];
  const float* w_off[4] = {(const float*)d_in[1], (const float*)d_in[5],
                           (const float*)d_in[9], (const float*)d_in[13]};
  const float* b_off[4] = {(const float*)d_in[2], (const float*)d_in[6],
                           (const float*)d_in[10], (const float*)d_in[14]};
  const float* w_c[4] = {(const float*)d_in[3], (const float*)d_in[7],
                         (const float*)d_in[11], (const float*)d_in[15]};
  const float* b_c[4] = {(const float*)d_in[4], (const float*)d_in[8],
                         (const float*)d_in[12], (const float*)d_in[16]};
  float* out = (float*)d_out;

  // Workspace (floats), lifetime-aliased; peak 7,166,464 f = 28.7 MB.
  float* ws = (float*)d_ws;
  float* a0 = ws;                  // [0, 65536)
  float* a1 = ws + 65536;          // [65536, 81920)
  float* a2 = ws + 81920;          // [81920, 344064)
  float* wT = ws + 344064;         // [344064, 422400)
  float* x1s = ws + 422400;        // [422400, 487936)
  float* off1 = ws + 487936;       // [487936, 506368)
  float* off0 = ws + 506368;       // [506368, 580096)
  float* off2 = ws + 580096;       // [580096, 875008)
  float* x2s = ws + 875008;        // [875008, 1923584)
  float* off3 = ws + 422400;       // ALIAS x1s..x2s-part; written after both dead
  float* x3s = ws + 1923584;       // [1923584, 6117888)
  float* a3 = ws + 6117888;        // [6117888, 7166464)
  float* wTd = wT;                 // 4 x 9216
  float* wTc = wT + 36864;         // 4 x 10368

  // 1. weight transpose + pyramid level 1/2 and 2x
  k_wtrans<<<cdiv(78336, BDIM), BDIM, 0, stream>>>(
      w_c[0], w_c[1], w_c[2], w_c[3], w_off[0], w_off[1], w_off[2], w_off[3], wT);
  k_resize12<<<cdiv(65536 + 1048576, BDIM), BDIM, 0, stream>>>(x, x1s, x2s);

  // 2. conv + deform for scales 0..2 (merged; cuts 16/80/336)
  CArgs ca;
  DArgs da;
  const float* ins[4] = {x1s, x, x2s, x3s};
  float* offs[4] = {off1, off0, off2, off3};
  float* as[4] = {a1, a0, a2, a3};
  for (int s = 0; s < 4; ++s) {
    ca.in[s] = ins[s];
    ca.wT[s] = wTc + s * 10368;
    ca.bias[s] = b_off[s];
    ca.out[s] = offs[s];
    da.in[s] = ins[s];
    da.off[s] = offs[s];
    da.wT[s] = wTd + (3 - s) * 9216;
    da.bias[s] = b_c[3 - s];
    da.out[s] = as[s];
  }
  ca.cut0 = 16; ca.cut1 = 80; ca.cut2 = 336;
  da.cut0 = 16; da.cut1 = 80; da.cut2 = 336;
  k_conv_all<<<336, 512, 0, stream>>>(ca);
  k_deform_all<<<336, 512, 0, stream>>>(da);

  // 3. x3s (needs x2s; x1s/off0-2 now dead)
  k_resize<<<cdiv(64 * 256 * 256, BDIM), BDIM, 0, stream>>>(x2s, x3s, 64, 128, 128, 256, 256);

  // 4. conv + deform for scale 3 (cuts 0/0/0 -> all blocks s=3)
  CArgs ca3 = ca;
  DArgs da3 = da;
  ca3.cut0 = 0; ca3.cut1 = 0; ca3.cut2 = 0;
  da3.cut0 = 0; da3.cut1 = 0; da3.cut2 = 0;
  k_conv_all<<<1024, 512, 0, stream>>>(ca3);
  k_deform_all<<<1024, 512, 0, stream>>>(da3);

  // 5. fused resize + gelu combine
  k_final<<<cdiv(65536, BDIM), BDIM, 0, stream>>>(a0, a1, a2, a3, out);
}

// Round 8
// 254.780 us; speedup vs baseline: 6.3472x; 1.0853x over previous
//
#include <hip/hip_runtime.h>
#include <math.h>

#define BDIM 256

// ---------------------------------------------------------------------------
// jax.image.resize (bilinear/triangle, antialias=True) tap weights.
// ---------------------------------------------------------------------------
__device__ __forceinline__ int resize_taps(int out_n, int o, int in_n,
                                           float* w, int* i0) {
  float inv_scale = (float)in_n / (float)out_n;
  float ks = inv_scale > 1.f ? inv_scale : 1.f;
  float sf = ((float)o + 0.5f) * inv_scale - 0.5f;
  int lo = (int)ceilf(sf - ks);
  int hi = (int)floorf(sf + ks);
  if (lo < 0) lo = 0;
  if (hi > in_n - 1) hi = in_n - 1;
  int n = hi - lo + 1;
  float sum = 0.f;
  for (int k = 0; k < n; ++k) {
    float t = 1.f - fabsf((float)(lo + k) - sf) / ks;
    t = t > 0.f ? t : 0.f;
    w[k] = t;
    sum += t;
  }
  float inv = 1.f / sum;
  for (int k = 0; k < n; ++k) w[k] *= inv;
  *i0 = lo;
  return n;
}

__device__ __forceinline__ float resize_one(const float* __restrict__ plane,
                                            int Hi, int Wi, int oy, int ox,
                                            int Ho, int Wo) {
  float wy[8], wx[8];
  int y0, x0;
  int ny = resize_taps(Ho, oy, Hi, wy, &y0);
  int nx = resize_taps(Wo, ox, Wi, wx, &x0);
  float acc = 0.f;
  for (int a = 0; a < ny; ++a) {
    const float* row = plane + (y0 + a) * Wi + x0;
    float r = 0.f;
    for (int b = 0; b < nx; ++b) r += wx[b] * row[b];
    acc += wy[a] * r;
  }
  return acc;
}

// x1s (64ch 64->32) and x2s (64ch 64->128) in one launch.
__global__ void k_resize12(const float* __restrict__ x, float* __restrict__ x1s,
                           float* __restrict__ x2s) {
  int idx = blockIdx.x * BDIM + threadIdx.x;
  if (idx < 64 * 32 * 32) {
    int ox = idx & 31, oy = (idx >> 5) & 31, c = idx >> 10;
    x1s[idx] = resize_one(x + c * 4096, 64, 64, oy, ox, 32, 32);
  } else {
    int j = idx - 65536;
    if (j < 64 * 128 * 128) {
      int ox = j & 127, oy = (j >> 7) & 127, c = j >> 14;
      x2s[j] = resize_one(x + c * 4096, 64, 64, oy, ox, 128, 128);
    }
  }
}

// generic (used for x3s: 64ch 128->256)
__global__ void k_resize(const float* __restrict__ in, float* __restrict__ out,
                         int C, int Hi, int Wi, int Ho, int Wo) {
  int idx = blockIdx.x * BDIM + threadIdx.x;
  if (idx >= C * Ho * Wo) return;
  int ox = idx % Wo;
  int t = idx / Wo;
  int oy = t % Ho;
  int c = t / Ho;
  out[idx] = resize_one(in + (size_t)c * Hi * Wi, Hi, Wi, oy, ox, Ho, Wo);
}

// ---------------------------------------------------------------------------
// Weight transpose: deform w_c[i] (16,64,3,3) -> [k][c][o] (9216 each);
// conv w_off[i] (18,64,3,3) -> [k][c][o] (10368 each) at base 36864.
// ---------------------------------------------------------------------------
__global__ void k_wtrans(const float* __restrict__ d0, const float* __restrict__ d1,
                         const float* __restrict__ d2, const float* __restrict__ d3,
                         const float* __restrict__ c0, const float* __restrict__ c1,
                         const float* __restrict__ c2, const float* __restrict__ c3,
                         float* __restrict__ dst) {
  int idx = blockIdx.x * BDIM + threadIdx.x;
  if (idx < 36864) {
    int i = idx / 9216, r = idx % 9216;
    int o = r % 16, t = r / 16, c = t % 64, k = t / 64;
    const float* s = i == 0 ? d0 : i == 1 ? d1 : i == 2 ? d2 : d3;
    dst[idx] = s[(o * 64 + c) * 9 + k];
  } else if (idx < 36864 + 41472) {
    int j = idx - 36864;
    int i = j / 10368, r = j % 10368;
    int o = r % 18, t = r / 18, c = t % 64, k = t / 64;
    const float* s = i == 0 ? c0 : i == 1 ? c1 : i == 2 ? c2 : c3;
    dst[idx] = s[(o * 64 + c) * 9 + k];
  }
}

// ---------------------------------------------------------------------------
// Merged 3x3 conv (Cin=64 -> 18). Block = 512 thr = 8 waves; wave g owns
// channels [8g,8g+8) for 64 px (lane). Weights [k][c][o] via uniform s_loads.
// launch_bounds(512,4): 128-VGPR budget (8/EU forced spill in R6).
// ---------------------------------------------------------------------------
struct CArgs {
  const float* in[4];
  const float* wT[4];
  const float* bias[4];
  float* out[4];
  int cut0, cut1, cut2;
};

__global__ __launch_bounds__(512, 4) void k_conv_all(CArgs A) {
  int b = blockIdx.x;
  int s = (b >= A.cut0) + (b >= A.cut1) + (b >= A.cut2);
  int b0 = (s == 0) ? 0 : (s == 1 ? A.cut0 : (s == 2 ? A.cut1 : A.cut2));
  int H = 32 << s, W = H, lw = 5 + s, HW = H * W;
  const float* in = A.in[s];
  const float* wT = A.wT[s];
  const float* bias = A.bias[s];
  float* out = A.out[s];
  int tid = threadIdx.x, lane = tid & 63;
  int g = __builtin_amdgcn_readfirstlane(tid >> 6);
  int p = (b - b0) * 64 + lane;
  int py = p >> lw, px = p & (W - 1);
  float acc[18];
#pragma unroll
  for (int o = 0; o < 18; ++o) acc[o] = 0.f;
  const float* ipg = in + (size_t)(g * 8) * HW;
#pragma unroll
  for (int ky = 0; ky < 3; ++ky) {
#pragma unroll
    for (int kx = 0; kx < 3; ++kx) {
      int k = ky * 3 + kx;
      int yy = py + ky - 1, xx = px + kx - 1;
      float msk = (yy >= 0 && yy < H && xx >= 0 && xx < W) ? 1.f : 0.f;
      int ai = min(max(yy, 0), H - 1) * W + min(max(xx, 0), W - 1);
      const float* ip = ipg + ai;
      const float* wk = wT + (size_t)(k * 64 + g * 8) * 18;
#pragma unroll
      for (int c = 0; c < 8; ++c, ip += HW, wk += 18) {
        float v = *ip * msk;
#pragma unroll
        for (int o = 0; o < 18; ++o) acc[o] += wk[o] * v;
      }
    }
  }
  __shared__ float red[7][64][19];
  int gv = tid >> 6;
  if (gv) {
#pragma unroll
    for (int o = 0; o < 18; ++o) red[gv - 1][lane][o] = acc[o];
  }
  __syncthreads();
  if (!gv) {
#pragma unroll
    for (int o = 0; o < 18; ++o) {
      float v = acc[o] + bias[o];
#pragma unroll
      for (int r = 0; r < 7; ++r) v += red[r][lane][o];
      out[(size_t)o * HW + p] = v;
    }
  }
}

// ---------------------------------------------------------------------------
// Merged deformable 3x3 conv (Cin=64 -> 16) + leaky. Block = 512 thr = 8
// waves; wave g owns channels [8g,8g+8) for 64 px. k-outer, taps on the fly;
// x-clamp folded into weight permutation. Weights [k][c][o].
// ---------------------------------------------------------------------------
struct DArgs {
  const float* in[4];
  const float* off[4];
  const float* wT[4];
  const float* bias[4];
  float* out[4];
  int cut0, cut1, cut2;
};

__global__ __launch_bounds__(512, 4) void k_deform_all(DArgs A) {
  int b = blockIdx.x;
  int s = (b >= A.cut0) + (b >= A.cut1) + (b >= A.cut2);
  int b0 = (s == 0) ? 0 : (s == 1 ? A.cut0 : (s == 2 ? A.cut1 : A.cut2));
  int H = 32 << s, W = H, lw = 5 + s, HW = H * W;
  int pad = 4 - s, dil = 4 - s;
  const float* in = A.in[s];
  const float* off = A.off[s];
  const float* wT = A.wT[s];
  const float* bias = A.bias[s];
  float* out = A.out[s];
  int tid = threadIdx.x, lane = tid & 63;
  int g = __builtin_amdgcn_readfirstlane(tid >> 6);
  int p = (b - b0) * 64 + lane;
  int py_ = p >> lw, px_ = p & (W - 1);

  float acc[16];
#pragma unroll
  for (int o = 0; o < 16; ++o) acc[o] = 0.f;
  const float* ipg = in + (size_t)(g * 8) * HW;
#pragma unroll
  for (int ky = 0; ky < 3; ++ky) {
#pragma unroll
    for (int kx = 0; kx < 3; ++kx) {
      int k = ky * 3 + kx;
      float dy = off[(size_t)(2 * k) * HW + p];
      float dx = off[(size_t)(2 * k + 1) * HW + p];
      float pyf = (float)(py_ - pad + ky * dil) + dy;
      float pxf = (float)(px_ - pad + kx * dil) + dx;
      float fy0 = floorf(pyf), fx0 = floorf(pxf);
      float wy = pyf - fy0, wxv = pxf - fx0;
      int y0 = (int)fy0, x0 = (int)fx0;
      float xg = (x0 >= -1 && x0 <= W - 1) ? 1.f : 0.f;
      float r0 = (1.f - wy) * ((y0 >= 0 && y0 < H) ? xg : 0.f);
      float r1 = wy * ((y0 + 1 >= 0 && y0 + 1 < H) ? xg : 0.f);
      float cl = 1.f - wxv, cr = wxv;
      bool xlo = x0 < 0, xhi = x0 > W - 2;
      float W00 = xlo ? r0 * cr : (xhi ? 0.f : r0 * cl);
      float W01 = xlo ? 0.f : (xhi ? r0 * cl : r0 * cr);
      float W10 = xlo ? r1 * cr : (xhi ? 0.f : r1 * cl);
      float W11 = xlo ? 0.f : (xhi ? r1 * cl : r1 * cr);
      int ax = min(max(x0, 0), W - 2);
      int cy0 = min(max(y0, 0), H - 1);
      int cy1 = min(max(y0 + 1, 0), H - 1);
      int A0 = cy0 * W + ax, A1 = cy1 * W + ax;
      const float* ip = ipg;
      const float* wk = wT + (size_t)(k * 64 + g * 8) * 16;
#pragma unroll
      for (int c = 0; c < 8; ++c, ip += HW, wk += 16) {
        const float* r0p = ip + A0;
        const float* r1p = ip + A1;
        float sv = W00 * r0p[0] + W01 * r0p[1] + W10 * r1p[0] + W11 * r1p[1];
#pragma unroll
        for (int o = 0; o < 16; ++o) acc[o] += wk[o] * sv;
      }
    }
  }
  __shared__ float red[7][64][17];
  int gv = tid >> 6;
  if (gv) {
#pragma unroll
    for (int o = 0; o < 16; ++o) red[gv - 1][lane][o] = acc[o];
  }
  __syncthreads();
  if (!gv) {
#pragma unroll
    for (int o = 0; o < 16; ++o) {
      float v = acc[o] + bias[o];
#pragma unroll
      for (int r = 0; r < 7; ++r) v += red[r][lane][o];
      v = v >= 0.f ? v : 0.01f * v;
      out[(size_t)o * HW + p] = v;
    }
  }
}

__device__ __forceinline__ float gelu_f(float x) {
  return 0.5f * x * (1.f + erff(x * 0.70710678118654752f));
}

// Fused: x1r/x2r/x3r gathered on the fly from a1/a2/a3, + gelu combine.
__global__ void k_final(const float* __restrict__ a0, const float* __restrict__ a1,
                        const float* __restrict__ a2, const float* __restrict__ a3,
                        float* __restrict__ out) {
  int i = blockIdx.x * BDIM + threadIdx.x;  // [0, 65536)
  int x = i & 63, y = (i >> 6) & 63, c = i >> 12;
  float x1r = resize_one(a1 + c * 1024, 32, 32, y, x, 64, 64);
  float x2r = resize_one(a2 + c * 16384, 128, 128, y, x, 64, 64);
  float x3r = resize_one(a3 + c * 65536, 256, 256, y, x, 64, 64);
  float av = a0[i];
  float l = gelu_f(x1r);
  float m = gelu_f(av - l);
  float h = gelu_f(x2r - av);
  float sv = gelu_f(x3r - x2r);
  out[i] = l;
  out[65536 + i] = m;
  out[131072 + i] = h;
  out[196608 + i] = sv;
}

static inline int cdiv(int a, int b) { return (a + b - 1) / b; }

extern "C" void kernel_launch(void* const* d_in, const int* in_sizes, int n_in,
                              void* d_out, int out_size, void* d_ws, size_t ws_size,
                              hipStream_t stream) {
  (void)in_sizes; (void)n_in; (void)out_size;
  const float* x = (const float*)d_in[0];
  const float* w_off[4] = {(const float*)d_in[1], (const float*)d_in[5],
                           (const float*)d_in[9], (const float*)d_in[13]};
  const float* b_off[4] = {(const float*)d_in[2], (const float*)d_in[6],
                           (const float*)d_in[10], (const float*)d_in[14]};
  const float* w_c[4] = {(const float*)d_in[3], (const float*)d_in[7],
                         (const float*)d_in[11], (const float*)d_in[15]};
  const float* b_c[4] = {(const float*)d_in[4], (const float*)d_in[8],
                         (const float*)d_in[12], (const float*)d_in[16]};
  float* out = (float*)d_out;

  // Common workspace prefix (floats)
  float* ws = (float*)d_ws;
  float* a0 = ws;                  // [0, 65536)
  float* a1 = ws + 65536;          // [65536, 81920)
  float* a2 = ws + 81920;          // [81920, 344064)
  float* wT = ws + 344064;         // [344064, 422400)
  float* x1s = ws + 422400;        // [422400, 487936)
  float* off1 = ws + 487936;       // [487936, 506368)
  float* off0 = ws + 506368;       // [506368, 580096)
  float* off2 = ws + 580096;       // [580096, 875008)
  float* x2s = ws + 875008;        // [875008, 1923584)
  float* x3s = ws + 1923584;       // [1923584, 6117888)
  float* a3 = ws + 6117888;        // [6117888, 7166464)
  float* wTd = wT;                 // 4 x 9216
  float* wTc = wT + 36864;         // 4 x 10368

  // off3: own region if ws allows full merge (33.4 MB), else alias x1s (R7).
  bool merged = ws_size >= (size_t)8346112 * 4;
  float* off3 = merged ? (ws + 7166464) : (ws + 422400);

  CArgs ca;
  DArgs da;
  const float* ins[4] = {x1s, x, x2s, x3s};
  float* offs[4] = {off1, off0, off2, off3};
  float* as[4] = {a1, a0, a2, a3};
  for (int s = 0; s < 4; ++s) {
    ca.in[s] = ins[s];
    ca.wT[s] = wTc + s * 10368;
    ca.bias[s] = b_off[s];
    ca.out[s] = offs[s];
    da.in[s] = ins[s];
    da.off[s] = offs[s];
    da.wT[s] = wTd + (3 - s) * 9216;
    da.bias[s] = b_c[3 - s];
    da.out[s] = as[s];
  }

  k_wtrans<<<cdiv(78336, BDIM), BDIM, 0, stream>>>(
      w_c[0], w_c[1], w_c[2], w_c[3], w_off[0], w_off[1], w_off[2], w_off[3], wT);
  k_resize12<<<cdiv(65536 + 1048576, BDIM), BDIM, 0, stream>>>(x, x1s, x2s);

  if (merged) {
    // x3s first, then one conv + one deform covering all 4 scales.
    k_resize<<<cdiv(64 * 256 * 256, BDIM), BDIM, 0, stream>>>(x2s, x3s, 64, 128, 128, 256, 256);
    ca.cut0 = 16; ca.cut1 = 80; ca.cut2 = 336;
    da.cut0 = 16; da.cut1 = 80; da.cut2 = 336;
    k_conv_all<<<1360, 512, 0, stream>>>(ca);
    k_deform_all<<<1360, 512, 0, stream>>>(da);
  } else {
    // R7 two-phase fallback (off3 aliases x1s region; x1s dead by phase 2).
    ca.cut0 = 16; ca.cut1 = 80; ca.cut2 = 336;
    da.cut0 = 16; da.cut1 = 80; da.cut2 = 336;
    k_conv_all<<<336, 512, 0, stream>>>(ca);
    k_deform_all<<<336, 512, 0, stream>>>(da);
    k_resize<<<cdiv(64 * 256 * 256, BDIM), BDIM, 0, stream>>>(x2s, x3s, 64, 128, 128, 256, 256);
    CArgs ca3 = ca;
    DArgs da3 = da;
    ca3.cut0 = 0; ca3.cut1 = 0; ca3.cut2 = 0;
    da3.cut0 = 0; da3.cut1 = 0; da3.cut2 = 0;
    k_conv_all<<<1024, 512, 0, stream>>>(ca3);
    k_deform_all<<<1024, 512, 0, stream>>>(da3);
  }

  k_final<<<cdiv(65536, BDIM), BDIM, 0, stream>>>(a0, a1, a2, a3, out);
}

// Round 9
// 249.903 us; speedup vs baseline: 6.4710x; 1.0195x over previous
//
#include <hip/hip_runtime.h>
#include <math.h>

#define BDIM 256

// ---------------------------------------------------------------------------
// jax.image.resize (bilinear/triangle, antialias=True) tap weights.
// ---------------------------------------------------------------------------
__device__ __forceinline__ int resize_taps(int out_n, int o, int in_n,
                                           float* w, int* i0) {
  float inv_scale = (float)in_n / (float)out_n;
  float ks = inv_scale > 1.f ? inv_scale : 1.f;
  float sf = ((float)o + 0.5f) * inv_scale - 0.5f;
  int lo = (int)ceilf(sf - ks);
  int hi = (int)floorf(sf + ks);
  if (lo < 0) lo = 0;
  if (hi > in_n - 1) hi = in_n - 1;
  int n = hi - lo + 1;
  float sum = 0.f;
  for (int k = 0; k < n; ++k) {
    float t = 1.f - fabsf((float)(lo + k) - sf) / ks;
    t = t > 0.f ? t : 0.f;
    w[k] = t;
    sum += t;
  }
  float inv = 1.f / sum;
  for (int k = 0; k < n; ++k) w[k] *= inv;
  *i0 = lo;
  return n;
}

__device__ __forceinline__ float resize_one(const float* __restrict__ plane,
                                            int Hi, int Wi, int oy, int ox,
                                            int Ho, int Wo) {
  float wy[8], wx[8];
  int y0, x0;
  int ny = resize_taps(Ho, oy, Hi, wy, &y0);
  int nx = resize_taps(Wo, ox, Wi, wx, &x0);
  float acc = 0.f;
  for (int a = 0; a < ny; ++a) {
    const float* row = plane + (y0 + a) * Wi + x0;
    float r = 0.f;
    for (int b = 0; b < nx; ++b) r += wx[b] * row[b];
    acc += wy[a] * r;
  }
  return acc;
}

// x1s (64ch 64->32) and x2s (64ch 64->128) in one launch.
__global__ void k_resize12(const float* __restrict__ x, float* __restrict__ x1s,
                           float* __restrict__ x2s) {
  int idx = blockIdx.x * BDIM + threadIdx.x;
  if (idx < 64 * 32 * 32) {
    int ox = idx & 31, oy = (idx >> 5) & 31, c = idx >> 10;
    x1s[idx] = resize_one(x + c * 4096, 64, 64, oy, ox, 32, 32);
  } else {
    int j = idx - 65536;
    if (j < 64 * 128 * 128) {
      int ox = j & 127, oy = (j >> 7) & 127, c = j >> 14;
      x2s[j] = resize_one(x + c * 4096, 64, 64, oy, ox, 128, 128);
    }
  }
}

// generic (used for x3s: 64ch 128->256)
__global__ void k_resize(const float* __restrict__ in, float* __restrict__ out,
                         int C, int Hi, int Wi, int Ho, int Wo) {
  int idx = blockIdx.x * BDIM + threadIdx.x;
  if (idx >= C * Ho * Wo) return;
  int ox = idx % Wo;
  int t = idx / Wo;
  int oy = t % Ho;
  int c = t / Ho;
  out[idx] = resize_one(in + (size_t)c * Hi * Wi, Hi, Wi, oy, ox, Ho, Wo);
}

// ---------------------------------------------------------------------------
// Weight transpose: deform w_c[i] (16,64,3,3) -> [k][c][o] (9216 each);
// conv w_off[i] (18,64,3,3) -> [k][c][o] (10368 each) at base 36864.
// ---------------------------------------------------------------------------
__global__ void k_wtrans(const float* __restrict__ d0, const float* __restrict__ d1,
                         const float* __restrict__ d2, const float* __restrict__ d3,
                         const float* __restrict__ c0, const float* __restrict__ c1,
                         const float* __restrict__ c2, const float* __restrict__ c3,
                         float* __restrict__ dst) {
  int idx = blockIdx.x * BDIM + threadIdx.x;
  if (idx < 36864) {
    int i = idx / 9216, r = idx % 9216;
    int o = r % 16, t = r / 16, c = t % 64, k = t / 64;
    const float* s = i == 0 ? d0 : i == 1 ? d1 : i == 2 ? d2 : d3;
    dst[idx] = s[(o * 64 + c) * 9 + k];
  } else if (idx < 36864 + 41472) {
    int j = idx - 36864;
    int i = j / 10368, r = j % 10368;
    int o = r % 18, t = r / 18, c = t % 64, k = t / 64;
    const float* s = i == 0 ? c0 : i == 1 ? c1 : i == 2 ? c2 : c3;
    dst[idx] = s[(o * 64 + c) * 9 + k];
  }
}

// ---------------------------------------------------------------------------
// FUSED offset-conv + deformable conv + leaky, all 4 scales in one grid.
// Block = 512 thr = 8 waves; wave g owns channels [8g,8g+8) for 64 px (lane).
// Phase A: partial conv18 -> LDS reduce -> per-thread off[18] in regs.
// Phase B: deform gathers using off; LDS reduce; wave 0 stores.
// Weights [k][c][o] via wave-uniform scalar loads. No off* buffers at all.
// ---------------------------------------------------------------------------
struct FArgs {
  const float* in[4];
  const float* wc[4];   // conv weights [k][c][o18]
  const float* bc[4];   // conv bias
  const float* wd[4];   // deform weights [k][c][o16] (crossed)
  const float* bd[4];   // deform bias (crossed)
  float* out[4];        // a1, a0, a2, a3
  int cut0, cut1, cut2;
};

__global__ __launch_bounds__(512, 4) void k_fused(FArgs A) {
  __shared__ float red[8][64][19];   // 38.9 KB
  int b = blockIdx.x;
  int s = (b >= A.cut0) + (b >= A.cut1) + (b >= A.cut2);
  int b0 = (s == 0) ? 0 : (s == 1 ? A.cut0 : (s == 2 ? A.cut1 : A.cut2));
  int H = 32 << s, W = H, lw = 5 + s, HW = H * W;
  int pad = 4 - s, dil = pad;
  const float* in = A.in[s];
  int tid = threadIdx.x, lane = tid & 63;
  int g = __builtin_amdgcn_readfirstlane(tid >> 6);
  int p = (b - b0) * 64 + lane;
  int py = p >> lw, px = p & (W - 1);
  const float* ipg = in + (size_t)(g * 8) * HW;

  // ---------------- phase A: offset conv (18 ch), partial over 8 channels
  {
    float accA[18];
#pragma unroll
    for (int o = 0; o < 18; ++o) accA[o] = 0.f;
    const float* wT = A.wc[s];
#pragma unroll
    for (int ky = 0; ky < 3; ++ky) {
#pragma unroll
      for (int kx = 0; kx < 3; ++kx) {
        int k = ky * 3 + kx;
        int yy = py + ky - 1, xx = px + kx - 1;
        float msk = (yy >= 0 && yy < H && xx >= 0 && xx < W) ? 1.f : 0.f;
        int ai = min(max(yy, 0), H - 1) * W + min(max(xx, 0), W - 1);
        const float* ip = ipg + ai;
        const float* wk = wT + (size_t)(k * 64 + g * 8) * 18;
#pragma unroll
        for (int c = 0; c < 8; ++c, ip += HW, wk += 18) {
          float v = *ip * msk;
#pragma unroll
          for (int o = 0; o < 18; ++o) accA[o] += wk[o] * v;
        }
      }
    }
    int gv = tid >> 6;
#pragma unroll
    for (int o = 0; o < 18; ++o) red[gv][lane][o] = accA[o];
  }
  __syncthreads();
  float off[18];
  {
    const float* bc = A.bc[s];
#pragma unroll
    for (int o = 0; o < 18; ++o) {
      float v = bc[o];
#pragma unroll
      for (int r = 0; r < 8; ++r) v += red[r][lane][o];
      off[o] = v;
    }
  }
  __syncthreads();   // all reads of red done before phase-B overwrites

  // ---------------- phase B: deformable conv (16 ch) using off
  float acc[16];
#pragma unroll
  for (int o = 0; o < 16; ++o) acc[o] = 0.f;
  {
    const float* wT = A.wd[s];
#pragma unroll
    for (int ky = 0; ky < 3; ++ky) {
#pragma unroll
      for (int kx = 0; kx < 3; ++kx) {
        int k = ky * 3 + kx;
        float dy = off[2 * k];
        float dx = off[2 * k + 1];
        float pyf = (float)(py - pad + ky * dil) + dy;
        float pxf = (float)(px - pad + kx * dil) + dx;
        float fy0 = floorf(pyf), fx0 = floorf(pxf);
        float wy = pyf - fy0, wxv = pxf - fx0;
        int y0 = (int)fy0, x0 = (int)fx0;
        float xg = (x0 >= -1 && x0 <= W - 1) ? 1.f : 0.f;
        float r0 = (1.f - wy) * ((y0 >= 0 && y0 < H) ? xg : 0.f);
        float r1 = wy * ((y0 + 1 >= 0 && y0 + 1 < H) ? xg : 0.f);
        float cl = 1.f - wxv, cr = wxv;
        bool xlo = x0 < 0, xhi = x0 > W - 2;
        float W00 = xlo ? r0 * cr : (xhi ? 0.f : r0 * cl);
        float W01 = xlo ? 0.f : (xhi ? r0 * cl : r0 * cr);
        float W10 = xlo ? r1 * cr : (xhi ? 0.f : r1 * cl);
        float W11 = xlo ? 0.f : (xhi ? r1 * cl : r1 * cr);
        int ax = min(max(x0, 0), W - 2);
        int cy0 = min(max(y0, 0), H - 1);
        int cy1 = min(max(y0 + 1, 0), H - 1);
        int A0 = cy0 * W + ax, A1 = cy1 * W + ax;
        const float* ip = ipg;
        const float* wk = wT + (size_t)(k * 64 + g * 8) * 16;
#pragma unroll
        for (int c = 0; c < 8; ++c, ip += HW, wk += 16) {
          const float* r0p = ip + A0;
          const float* r1p = ip + A1;
          float sv = W00 * r0p[0] + W01 * r0p[1] + W10 * r1p[0] + W11 * r1p[1];
#pragma unroll
          for (int o = 0; o < 16; ++o) acc[o] += wk[o] * sv;
        }
      }
    }
  }
  int gv = tid >> 6;
  if (gv) {
#pragma unroll
    for (int o = 0; o < 16; ++o) red[gv - 1][lane][o] = acc[o];
  }
  __syncthreads();
  if (!gv) {
    const float* bd = A.bd[s];
    float* out = A.out[s];
#pragma unroll
    for (int o = 0; o < 16; ++o) {
      float v = acc[o] + bd[o];
#pragma unroll
      for (int r = 0; r < 7; ++r) v += red[r][lane][o];
      v = v >= 0.f ? v : 0.01f * v;
      out[(size_t)o * HW + p] = v;
    }
  }
}

// ---------------------------------------------------------------------------
// Horizontal downsample pass: a3 (16,256,256) -> t3 (16,256,64) 8 taps;
// a2 (16,128,128) -> t2 (16,128,64) 4 taps.
// ---------------------------------------------------------------------------
__global__ void k_hpass(const float* __restrict__ a2, const float* __restrict__ a3,
                        float* __restrict__ t2, float* __restrict__ t3) {
  int idx = blockIdx.x * BDIM + threadIdx.x;
  if (idx < 262144) {
    int ox = idx & 63, y = (idx >> 6) & 255, c = idx >> 14;
    float wx[8];
    int x0;
    int n = resize_taps(64, ox, 256, wx, &x0);
    const float* row = a3 + (size_t)c * 65536 + y * 256 + x0;
    float r = 0.f;
    for (int b = 0; b < n; ++b) r += wx[b] * row[b];
    t3[idx] = r;
  } else {
    int j = idx - 262144;
    if (j < 131072) {
      int ox = j & 63, y = (j >> 6) & 127, c = j >> 13;
      float wx[8];
      int x0;
      int n = resize_taps(64, ox, 128, wx, &x0);
      const float* row = a2 + (size_t)c * 16384 + y * 128 + x0;
      float r = 0.f;
      for (int b = 0; b < n; ++b) r += wx[b] * row[b];
      t2[j] = r;
    }
  }
}

__device__ __forceinline__ float gelu_f(float x) {
  return 0.5f * x * (1.f + erff(x * 0.70710678118654752f));
}

// Vertical taps + gelu combine.
__global__ void k_final2(const float* __restrict__ a0, const float* __restrict__ a1,
                         const float* __restrict__ t2, const float* __restrict__ t3,
                         float* __restrict__ out) {
  int i = blockIdx.x * BDIM + threadIdx.x;  // [0, 65536)
  int x = i & 63, y = (i >> 6) & 63, c = i >> 12;
  float x1r = resize_one(a1 + c * 1024, 32, 32, y, x, 64, 64);
  float wv[8];
  int y0;
  int n2 = resize_taps(64, y, 128, wv, &y0);
  const float* tp2 = t2 + (size_t)c * 8192 + y0 * 64 + x;
  float x2r = 0.f;
  for (int a = 0; a < n2; ++a) x2r += wv[a] * tp2[a * 64];
  int n3 = resize_taps(64, y, 256, wv, &y0);
  const float* tp3 = t3 + (size_t)c * 16384 + y0 * 64 + x;
  float x3r = 0.f;
  for (int a = 0; a < n3; ++a) x3r += wv[a] * tp3[a * 64];
  float av = a0[i];
  float l = gelu_f(x1r);
  float m = gelu_f(av - l);
  float h = gelu_f(x2r - av);
  float sv = gelu_f(x3r - x2r);
  out[i] = l;
  out[65536 + i] = m;
  out[131072 + i] = h;
  out[196608 + i] = sv;
}

static inline int cdiv(int a, int b) { return (a + b - 1) / b; }

extern "C" void kernel_launch(void* const* d_in, const int* in_sizes, int n_in,
                              void* d_out, int out_size, void* d_ws, size_t ws_size,
                              hipStream_t stream) {
  (void)in_sizes; (void)n_in; (void)out_size; (void)ws_size;
  const float* x = (const float*)d_in[0];
  const float* w_off[4] = {(const float*)d_in[1], (const float*)d_in[5],
                           (const float*)d_in[9], (const float*)d_in[13]};
  const float* b_off[4] = {(const float*)d_in[2], (const float*)d_in[6],
                           (const float*)d_in[10], (const float*)d_in[14]};
  const float* w_c[4] = {(const float*)d_in[3], (const float*)d_in[7],
                         (const float*)d_in[11], (const float*)d_in[15]};
  const float* b_c[4] = {(const float*)d_in[4], (const float*)d_in[8],
                         (const float*)d_in[12], (const float*)d_in[16]};
  float* out = (float*)d_out;

  // Workspace (floats), lifetime-aliased; peak 7,166,464 f = 28.7 MB.
  float* ws = (float*)d_ws;
  float* a0 = ws;                  // [0, 65536)
  float* a1 = ws + 65536;          // [65536, 81920)
  float* a2 = ws + 81920;          // [81920, 344064)
  float* wT = ws + 344064;         // [344064, 422400)
  float* x1s = ws + 422400;        // [422400, 487936)   dead after k_fused
  float* t3 = ws + 422400;         // ALIAS x1s+ (written post-fused)
  float* t2 = ws + 684544;         // [684544, 815616)
  float* x2s = ws + 875008;        // [875008, 1923584)
  float* x3s = ws + 1923584;       // [1923584, 6117888)
  float* a3 = ws + 6117888;        // [6117888, 7166464)
  float* wTd = wT;                 // 4 x 9216
  float* wTc = wT + 36864;         // 4 x 10368

  FArgs fa;
  const float* ins[4] = {x1s, x, x2s, x3s};
  float* as[4] = {a1, a0, a2, a3};
  for (int s = 0; s < 4; ++s) {
    fa.in[s] = ins[s];
    fa.wc[s] = wTc + s * 10368;
    fa.bc[s] = b_off[s];
    fa.wd[s] = wTd + (3 - s) * 9216;
    fa.bd[s] = b_c[3 - s];
    fa.out[s] = as[s];
  }
  fa.cut0 = 16; fa.cut1 = 80; fa.cut2 = 336;

  k_wtrans<<<cdiv(78336, BDIM), BDIM, 0, stream>>>(
      w_c[0], w_c[1], w_c[2], w_c[3], w_off[0], w_off[1], w_off[2], w_off[3], wT);
  k_resize12<<<cdiv(65536 + 1048576, BDIM), BDIM, 0, stream>>>(x, x1s, x2s);
  k_resize<<<cdiv(64 * 256 * 256, BDIM), BDIM, 0, stream>>>(x2s, x3s, 64, 128, 128, 256, 256);
  k_fused<<<1360, 512, 0, stream>>>(fa);
  k_hpass<<<cdiv(262144 + 131072, BDIM), BDIM, 0, stream>>>(a2, a3, t2, t3);
  k_final2<<<cdiv(65536, BDIM), BDIM, 0, stream>>>(a0, a1, t2, t3, out);
}